// Round 6
// baseline (139.136 us; speedup 1.0000x reference)
//
#include <hip/hip_runtime.h>

#define NN 256
#define DIN 32
#define DD 64
#define D2 128
#define RTOT 4096      // BB*NN rows
#define GB 256         // blocks (= CUs; must all be co-resident)
#define RPB 16         // rows per block
#define JC 64          // j-chunk for agg

typedef float f32x4 __attribute__((ext_vector_type(4)));

struct Params {
  const float *fea, *adj, *encW, *encb, *bondW, *eps, *W1, *b1, *g1, *be1,
              *W2, *b2, *gbn, *bbn;
  float *out, *x, *ctrl;   // ctrl: [0..16) counter, +16: per-layer stat accs
};

__device__ __forceinline__ void fma4(f32x4& o, float s, const f32x4 w) {
  o[0] = fmaf(s, w[0], o[0]); o[1] = fmaf(s, w[1], o[1]);
  o[2] = fmaf(s, w[2], o[2]); o[3] = fmaf(s, w[3], o[3]);
}

// ---- coherent (cross-XCD) access: sc0 sc1 bypass the non-coherent caches ----
__device__ __forceinline__ f32x4 cload4(const float* p) {
  f32x4 r;
  asm volatile("global_load_dwordx4 %0, %1, off sc0 sc1\n\ts_waitcnt vmcnt(0)"
               : "=&v"(r) : "v"(p) : "memory");
  return r;
}
__device__ __forceinline__ void cload16(const float* p, f32x4& a, f32x4& b,
                                        f32x4& c, f32x4& d) {
  asm volatile(
      "global_load_dwordx4 %0, %4, off sc0 sc1\n\t"
      "global_load_dwordx4 %1, %4, off offset:16 sc0 sc1\n\t"
      "global_load_dwordx4 %2, %4, off offset:32 sc0 sc1\n\t"
      "global_load_dwordx4 %3, %4, off offset:48 sc0 sc1\n\t"
      "s_waitcnt vmcnt(0)"
      : "=&v"(a), "=&v"(b), "=&v"(c), "=&v"(d)
      : "v"(p) : "memory");
}
__device__ __forceinline__ float cload1(const float* p) {
  float r;
  asm volatile("global_load_dword %0, %1, off sc0 sc1\n\ts_waitcnt vmcnt(0)"
               : "=&v"(r) : "v"(p) : "memory");
  return r;
}
__device__ __forceinline__ void cstore4(float* p, f32x4 v) {
  asm volatile("global_store_dwordx4 %0, %1, off sc0 sc1"
               :: "v"(p), "v"(v) : "memory");
}

// relaxed everywhere: no buffer_wb/inv — cross-block data goes via sc ops only
__device__ __forceinline__ void gridbar(unsigned* cnt, unsigned target) {
  asm volatile("s_waitcnt vmcnt(0)" ::: "memory");  // drain our asm sc-stores
  __syncthreads();
  if (threadIdx.x == 0) {
    __hip_atomic_fetch_add(cnt, 1u, __ATOMIC_RELAXED, __HIP_MEMORY_SCOPE_AGENT);
    while (__hip_atomic_load(cnt, __ATOMIC_RELAXED, __HIP_MEMORY_SCOPE_AGENT) < target)
      __builtin_amdgcn_s_sleep(2);
  }
  __syncthreads();
}

// LDS map (floats): W[0,8192) SY[8192,12416) SH[12416,13440) H1[13440,15488)
//                   sbw[15488,15552) SB[15552,15808)
__global__ __launch_bounds__(256, 1) void fused(Params p) {
  __shared__ float smem[15808];   // 61.75 KB
  const int tid = threadIdx.x, bid = blockIdx.x;
  const int lane = tid & 63, wv = tid >> 6;
  const int b = bid >> 4;              // batch
  const int gr0 = bid * RPB;           // global row base (owns 16 rows)

  unsigned* cnt = (unsigned*)p.ctrl;
  float* accs = p.ctrl + 16;           // per layer: 1s[128] 1q[128] 2s[64] 2q[64]

  float* sW  = smem;
  float* sSY = smem + 8192;
  float* sH  = smem + 12416;
  float* sH1 = smem + 13440;           // first 1024 doubles as sadj during agg
  float* sbw = smem + 15488;
  float* sSB = smem + 15552;           // bc/fin: S2@0(64) B2@64(64); d: Sd@0(128) Bd@128(128)

  unsigned tgt = 256;

  // ---------------- enc: own 16 rows ----------------
  {
    int lr = tid >> 4, c0 = (tid & 15) * 4;
    const float* fr = p.fea + (gr0 + lr) * DIN;
    f32x4 o = { p.encb[c0], p.encb[c0 + 1], p.encb[c0 + 2], p.encb[c0 + 3] };
#pragma unroll
    for (int k = 0; k < DIN; ++k) {
      float fv = fr[k];
      const float* wr = p.encW + k * DD + c0;
      o[0] = fmaf(fv, wr[0], o[0]); o[1] = fmaf(fv, wr[1], o[1]);
      o[2] = fmaf(fv, wr[2], o[2]); o[3] = fmaf(fv, wr[3], o[3]);
    }
    cstore4(&p.x[(size_t)(gr0 + lr) * DD + c0], o);
  }
  gridbar(cnt, tgt); tgt += 256;

  for (int l = 0; l < 3; ++l) {
    // ================= bc: agg + h + MLP1 -> h1(LDS), stats -> acc1 =================
    {
      const f32x4* w4 = (const f32x4*)(p.W1 + l * DD * D2);
      f32x4* sW4 = (f32x4*)sW;
#pragma unroll
      for (int i = 0; i < 8; ++i) sW4[tid + i * 256] = w4[tid + i * 256];
      if (tid < DD) sbw[tid] = p.bondW[l * DD + tid];
      if (l > 0 && tid < DD) {
        const float* a2 = accs + (l - 1) * 384;
        float s = cload1(a2 + 256 + tid);
        float q = cload1(a2 + 320 + tid);
        float mean = s * (1.f / RTOT);
        float var = fmaf(-mean, mean, q * (1.f / RTOT));
        float sc = p.gbn[(l - 1) * DD + tid] * rsqrtf(var + 1e-5f);
        sSB[tid] = sc;
        sSB[64 + tid] = fmaf(-mean, sc, p.bbn[(l - 1) * DD + tid]);
      }

      float acc[4] = {0.f, 0.f, 0.f, 0.f};
      float* sadj = sH1;
      const float* adjb = p.adj + ((size_t)b * NN + (bid & 15) * RPB) * NN;

      for (int jc = 0; jc < NN; jc += JC) {
        __syncthreads();   // fences staging above (1st iter) / sy-sadj reuse
        {
          int row = tid >> 2, ds = (tid & 3) * 16;
          const float* src = p.x + (size_t)(b * NN + jc + row) * DD + ds;
          f32x4 v0, v1, v2, v3;
          cload16(src, v0, v1, v2, v3);
          f32x4 vv[4] = {v0, v1, v2, v3};
          float* dst = sSY + row * DD + ds;
#pragma unroll
          for (int q = 0; q < 4; ++q)
#pragma unroll
            for (int e = 0; e < 4; ++e) {
              int dch = ds + q * 4 + e;
              float v = vv[q][e];
              if (l > 0) v = fmaxf(fmaf(v, sSB[dch], sSB[64 + dch]), 0.f);
              dst[q * 4 + e] = fmaxf(v + sbw[dch], 0.f);
            }
        }
        {
          int lr = tid >> 4, c4 = (tid & 15) * 4;
          *(f32x4*)&sadj[lr * JC + c4] =
              *(const f32x4*)(adjb + (size_t)lr * NN + jc + c4);
        }
        __syncthreads();
        unsigned long long m[4];
#pragma unroll
        for (int k = 0; k < 4; ++k)
          m[k] = __ballot(sadj[(wv * 4 + k) * JC + lane] != 0.f);
        while (m[0] | m[1] | m[2] | m[3]) {
          float v[8]; bool hb[8];
#pragma unroll
          for (int k = 0; k < 4; ++k) {
            bool b0 = m[k] != 0ull;
            int j0 = b0 ? __builtin_ctzll(m[k]) : 0;
            m[k] &= m[k] - 1;
            bool b1 = m[k] != 0ull;
            int j1 = b1 ? __builtin_ctzll(m[k]) : 0;
            m[k] &= m[k] - 1;
            hb[2 * k] = b0; hb[2 * k + 1] = b1;
            v[2 * k] = sSY[j0 * DD + lane];
            v[2 * k + 1] = sSY[j1 * DD + lane];
          }
#pragma unroll
          for (int k = 0; k < 4; ++k)
            acc[k] += (hb[2 * k] ? v[2 * k] : 0.f) + (hb[2 * k + 1] ? v[2 * k + 1] : 0.f);
        }
      }

      // h = (1+eps)*xv + acc  (two-pass via LDS to keep cload4 coalesced)
#pragma unroll
      for (int k = 0; k < 4; ++k) sH[(wv * 4 + k) * DD + lane] = acc[k];
      __syncthreads();
      {
        int row = tid >> 4, c0 = (tid & 15) * 4;
        f32x4 xv = cload4(&p.x[(size_t)(gr0 + row) * DD + c0]);
        float epv = 1.f + p.eps[l];
        float* hh = sH + row * DD + c0;
#pragma unroll
        for (int e = 0; e < 4; ++e) {
          float v = xv[e];
          int dch = c0 + e;
          if (l > 0) v = fmaxf(fmaf(v, sSB[dch], sSB[64 + dch]), 0.f);
          hh[e] = fmaf(epv, v, hh[e]);
        }
      }
      __syncthreads();

      // MLP1: 16x128, thread = 2 rows x 4 cols; h1 stays in LDS
      {
        int rg = tid >> 5, c0 = (tid & 31) * 4;
        f32x4 bv = *(const f32x4*)&p.b1[l * D2 + c0];
        f32x4 o0 = bv, o1 = bv;
        for (int d = 0; d < DD; d += 4) {
          f32x4 s0 = *(const f32x4*)&sH[(rg * 2 + 0) * DD + d];
          f32x4 s1 = *(const f32x4*)&sH[(rg * 2 + 1) * DD + d];
          f32x4 w0 = *(const f32x4*)&sW[(d + 0) * D2 + c0];
          f32x4 w1 = *(const f32x4*)&sW[(d + 1) * D2 + c0];
          f32x4 w2 = *(const f32x4*)&sW[(d + 2) * D2 + c0];
          f32x4 w3 = *(const f32x4*)&sW[(d + 3) * D2 + c0];
          fma4(o0, s0[0], w0); fma4(o0, s0[1], w1); fma4(o0, s0[2], w2); fma4(o0, s0[3], w3);
          fma4(o1, s1[0], w0); fma4(o1, s1[1], w1); fma4(o1, s1[2], w2); fma4(o1, s1[3], w3);
        }
        *(f32x4*)&sH1[(rg * 2 + 0) * D2 + c0] = o0;
        *(f32x4*)&sH1[(rg * 2 + 1) * D2 + c0] = o1;
        *(f32x4*)&sSY[rg * D2 + c0] = o0 + o1;                 // psum [8][128]
        *(f32x4*)&sSY[1024 + rg * D2 + c0] = o0 * o0 + o1 * o1; // psq
      }
      __syncthreads();
      if (tid < D2) {
        float s = 0.f, q = 0.f;
#pragma unroll
        for (int g = 0; g < 8; ++g) { s += sSY[g * D2 + tid]; q += sSY[1024 + g * D2 + tid]; }
        float* a1 = accs + l * 384;
        atomicAdd(a1 + tid, s);
        atomicAdd(a1 + 128 + tid, q);
      }
    }
    gridbar(cnt, tgt); tgt += 256;

    // ================= d: BN1+ReLU + MLP2 -> x (coherent), stats -> acc2 =================
    {
      const f32x4* w4 = (const f32x4*)(p.W2 + l * D2 * DD);
      f32x4* sW4 = (f32x4*)sW;
#pragma unroll
      for (int i = 0; i < 8; ++i) sW4[tid + i * 256] = w4[tid + i * 256];
      if (tid < D2) {
        const float* a1 = accs + l * 384;
        float s = cload1(a1 + tid);
        float q = cload1(a1 + 128 + tid);
        float mean = s * (1.f / RTOT);
        float var = fmaf(-mean, mean, q * (1.f / RTOT));
        float sc = p.g1[l * D2 + tid] * rsqrtf(var + 1e-5f);
        sSB[tid] = sc;
        sSB[128 + tid] = fmaf(-mean, sc, p.be1[l * D2 + tid]);
      }
      __syncthreads();
#pragma unroll
      for (int ii = 0; ii < 2; ++ii) {           // BN+ReLU: h1(LDS) -> sh1 (SY, stride 132)
        int i = tid + ii * 256;
        f32x4 v = ((const f32x4*)sH1)[i];
        int lr = i >> 5, c = (i & 31) * 4;
#pragma unroll
        for (int e = 0; e < 4; ++e)
          v[e] = fmaxf(fmaf(v[e], sSB[c + e], sSB[128 + c + e]), 0.f);
        *(f32x4*)&sSY[lr * 132 + c] = v;
      }
      __syncthreads();
      {
        int row = tid >> 4, c0 = (tid & 15) * 4;  // MLP2: 1 row x 4 cols, all 4 waves
        f32x4 o = *(const f32x4*)&p.b2[l * DD + c0];
        for (int c = 0; c < D2; c += 4) {
          f32x4 s4 = *(const f32x4*)&sSY[row * 132 + c];
          f32x4 w0 = *(const f32x4*)&sW[(c + 0) * DD + c0];
          f32x4 w1 = *(const f32x4*)&sW[(c + 1) * DD + c0];
          f32x4 w2 = *(const f32x4*)&sW[(c + 2) * DD + c0];
          f32x4 w3 = *(const f32x4*)&sW[(c + 3) * DD + c0];
          fma4(o, s4[0], w0); fma4(o, s4[1], w1); fma4(o, s4[2], w2); fma4(o, s4[3], w3);
        }
        cstore4(&p.x[(size_t)(gr0 + row) * DD + c0], o);   // raw h2, coherent
        *(f32x4*)&sSY[2176 + row * DD + c0] = o;           // psum2 [16][64]
        *(f32x4*)&sSY[3200 + row * DD + c0] = o * o;       // psq2
      }
      __syncthreads();
      if (tid < DD) {
        float s = 0.f, q = 0.f;
#pragma unroll
        for (int g = 0; g < 16; ++g) { s += sSY[2176 + g * DD + tid]; q += sSY[3200 + g * DD + tid]; }
        float* a2 = accs + l * 384;
        atomicAdd(a2 + 256 + tid, s);
        atomicAdd(a2 + 320 + tid, q);
      }
    }
    gridbar(cnt, tgt); tgt += 256;
  }

  // ================= final BN2 (no relu) on own rows =================
  {
    if (tid < DD) {
      const float* a2 = accs + 2 * 384;
      float s = cload1(a2 + 256 + tid);
      float q = cload1(a2 + 320 + tid);
      float mean = s * (1.f / RTOT);
      float var = fmaf(-mean, mean, q * (1.f / RTOT));
      float sc = p.gbn[2 * DD + tid] * rsqrtf(var + 1e-5f);
      sSB[tid] = sc;
      sSB[64 + tid] = fmaf(-mean, sc, p.bbn[2 * DD + tid]);
    }
    __syncthreads();
    int row = tid >> 4, c0 = (tid & 15) * 4;
    f32x4 v = cload4(&p.x[(size_t)(gr0 + row) * DD + c0]);
#pragma unroll
    for (int e = 0; e < 4; ++e) v[e] = fmaf(v[e], sSB[c0 + e], sSB[64 + c0 + e]);
    *(f32x4*)&p.out[(size_t)(gr0 + row) * DD + c0] = v;
  }
}

extern "C" void kernel_launch(void* const* d_in, const int* in_sizes, int n_in,
                              void* d_out, int out_size, void* d_ws, size_t ws_size,
                              hipStream_t stream) {
  Params prm;
  prm.fea  = (const float*)d_in[0];
  prm.adj  = (const float*)d_in[1];
  prm.encW = (const float*)d_in[2];
  prm.encb = (const float*)d_in[3];
  prm.bondW= (const float*)d_in[4];
  prm.eps  = (const float*)d_in[5];
  prm.W1   = (const float*)d_in[6];
  prm.b1   = (const float*)d_in[7];
  prm.g1   = (const float*)d_in[8];
  prm.be1  = (const float*)d_in[9];
  prm.W2   = (const float*)d_in[10];
  prm.b2   = (const float*)d_in[11];
  prm.gbn  = (const float*)d_in[12];
  prm.bbn  = (const float*)d_in[13];
  prm.out  = (float*)d_out;
  float* ws = (float*)d_ws;
  prm.x    = ws;                 // 262144 floats
  prm.ctrl = ws + 262144;        // counter + 3*384 stat accumulators

  // zero barrier counter + stat accumulators every launch (graph-capture-safe)
  hipMemsetAsync(prm.ctrl, 0, 8192, stream);
  fused<<<GB, 256, 0, stream>>>(prm);
}

// Round 7
// 134.188 us; speedup vs baseline: 1.0369x; 1.0369x over previous
//
#include <hip/hip_runtime.h>

#define NN 256
#define DIN 32
#define DD 64
#define D2 128
#define RTOT 4096      // BB*NN rows
#define GB 256         // blocks (= CUs; co-resident)
#define RPB 16         // rows per block
#define JC 64          // j-chunk for agg

typedef float f32x4 __attribute__((ext_vector_type(4)));

struct Params {
  const float *fea, *adj, *encW, *encb, *bondW, *eps, *W1, *b1, *g1, *be1,
              *W2, *b2, *gbn, *bbn;
  float *out, *x, *ctrl;   // ctrl: [0..16) counter, +16: per-layer stat accs
};

__device__ __forceinline__ void fma4(f32x4& o, float s, const f32x4 w) {
  o[0] = fmaf(s, w[0], o[0]); o[1] = fmaf(s, w[1], o[1]);
  o[2] = fmaf(s, w[2], o[2]); o[3] = fmaf(s, w[3], o[3]);
}

// ---- coherent (cross-XCD) access: sc0 sc1 bypass the non-coherent caches ----
__device__ __forceinline__ float cload1(const float* p) {
  float r;
  asm volatile("global_load_dword %0, %1, off sc0 sc1\n\ts_waitcnt vmcnt(0)"
               : "=&v"(r) : "v"(p) : "memory");
  return r;
}
__device__ __forceinline__ void cstore4(float* p, f32x4 v) {
  asm volatile("global_store_dwordx4 %0, %1, off sc0 sc1"
               :: "v"(p), "v"(v) : "memory");
}
// issue 4 independent coherent loads WITHOUT waiting (pipeline issue half)
__device__ __forceinline__ void cissue4(const f32x4* p0, const f32x4* p1,
                                        const f32x4* p2, const f32x4* p3,
                                        f32x4& a, f32x4& b, f32x4& c, f32x4& d) {
  asm volatile(
      "global_load_dwordx4 %0, %4, off sc0 sc1\n\t"
      "global_load_dwordx4 %1, %5, off sc0 sc1\n\t"
      "global_load_dwordx4 %2, %6, off sc0 sc1\n\t"
      "global_load_dwordx4 %3, %7, off sc0 sc1"
      : "=&v"(a), "=&v"(b), "=&v"(c), "=&v"(d)
      : "v"(p0), "v"(p1), "v"(p2), "v"(p3) : "memory");
}
__device__ __forceinline__ void cwait() {
  asm volatile("s_waitcnt vmcnt(0)" ::: "memory");
}

// relaxed split barrier: no acquire/release fences -> no L2 wb/inv.
// cross-block data travels only via sc0sc1 ops and device-scope atomics.
__device__ __forceinline__ void bar_arrive(unsigned* cnt) {
  cwait();            // drain this thread's sc-stores / stat atomics
  __syncthreads();
  if (threadIdx.x == 0)
    __hip_atomic_fetch_add(cnt, 1u, __ATOMIC_RELAXED, __HIP_MEMORY_SCOPE_AGENT);
}
__device__ __forceinline__ void bar_wait(unsigned* cnt, unsigned target) {
  if (threadIdx.x == 0) {
    while (__hip_atomic_load(cnt, __ATOMIC_RELAXED, __HIP_MEMORY_SCOPE_AGENT) < target)
      __builtin_amdgcn_s_sleep(2);
  }
  __syncthreads();
}

// LDS map (floats): sW[0,8192) sSY[8192,12416) sH[12416,13440) sH1[13440,15488)
//                   sbw[15488,15552) sSB[15552,15808)
__global__ __launch_bounds__(256, 1) void fused(Params p) {
  __shared__ float smem[15808];   // 61.75 KB
  const int tid = threadIdx.x, bid = blockIdx.x;
  const int lane = tid & 63, wv = tid >> 6;
  const int b = bid >> 4;              // batch
  const int gr0 = bid * RPB;           // global row base (owns 16 rows)
  const int row = tid >> 4, cb = (tid & 15) * 4;  // own-row layout

  unsigned* cnt = (unsigned*)p.ctrl;
  float* accs = p.ctrl + 16;           // per layer: 1s[128] 1q[128] 2s[64] 2q[64]

  float* sW  = smem;
  float* sSY = smem + 8192;
  float* sH  = smem + 12416;
  float* sH1 = smem + 13440;           // doubles as sadj during agg
  float* sbw = smem + 15488;
  float* sSB = smem + 15552;

  unsigned tgt = 256;
  f32x4 xown;   // this thread's slice of x[gr0+row][cb..cb+3] (raw, pre-BN)

  // ---------------- enc ----------------
  {
    const float* fr = p.fea + (gr0 + row) * DIN;
    f32x4 o = *(const f32x4*)&p.encb[cb];
#pragma unroll
    for (int k = 0; k < DIN; ++k) {
      float fv = fr[k];
      const float* wr = p.encW + k * DD + cb;
      o[0] = fmaf(fv, wr[0], o[0]); o[1] = fmaf(fv, wr[1], o[1]);
      o[2] = fmaf(fv, wr[2], o[2]); o[3] = fmaf(fv, wr[3], o[3]);
    }
    xown = o;
    cstore4(&p.x[(size_t)(gr0 + row) * DD + cb], o);
  }
  bar_arrive(cnt);
  {  // stage W1(0) + bondW(0) in the barrier gap
    const f32x4* w4 = (const f32x4*)p.W1;
    f32x4* s4 = (f32x4*)sW;
#pragma unroll
    for (int i = 0; i < 8; ++i) s4[tid + i * 256] = w4[tid + i * 256];
    if (tid < DD) sbw[tid] = p.bondW[tid];
  }
  bar_wait(cnt, tgt); tgt += 256;

  for (int l = 0; l < 3; ++l) {
    // ============ bc: agg + h + MLP1 -> h1(LDS), stats -> accs ============
    {
      if (l > 0 && tid < DD) {     // prev-layer BN2 affine from global accs
        const float* a2 = accs + (l - 1) * 384;
        float s = cload1(a2 + 256 + tid);
        float q = cload1(a2 + 320 + tid);
        float mean = s * (1.f / RTOT);
        float var = fmaf(-mean, mean, q * (1.f / RTOT));
        float sc = p.gbn[(l - 1) * DD + tid] * rsqrtf(var + 1e-5f);
        sSB[tid] = sc;
        sSB[64 + tid] = fmaf(-mean, sc, p.bbn[(l - 1) * DD + tid]);
      }
      const f32x4* xb4 = (const f32x4*)(p.x + (size_t)b * NN * DD);
      f32x4 r0, r1, r2, r3;
      cissue4(xb4 + tid, xb4 + tid + 256, xb4 + tid + 512, xb4 + tid + 768,
              r0, r1, r2, r3);
      __syncthreads();   // fences sW/sbw/sSB staging before use
      f32x4 bw4 = *(const f32x4*)&sbw[cb];
      f32x4 aS = {0,0,0,0}, aB = {0,0,0,0};
      if (l > 0) { aS = *(const f32x4*)&sSB[cb]; aB = *(const f32x4*)&sSB[64 + cb]; }
      float epv = 1.f + p.eps[l];

      float acc0 = 0.f, acc1 = 0.f, acc2 = 0.f, acc3 = 0.f;
      const float* adjb = p.adj + ((size_t)b * NN + (bid & 15) * RPB) * NN;
      float* sadj = sH1;

      for (int jc = 0; jc < NN; jc += JC) {
        cwait();                       // loads for THIS chunk arrived
        f32x4 y0 = r0, y1 = r1, y2 = r2, y3 = r3;
#pragma unroll
        for (int e = 0; e < 4; ++e) {
          if (l > 0) {
            y0[e] = fmaxf(fmaf(y0[e], aS[e], aB[e]), 0.f);
            y1[e] = fmaxf(fmaf(y1[e], aS[e], aB[e]), 0.f);
            y2[e] = fmaxf(fmaf(y2[e], aS[e], aB[e]), 0.f);
            y3[e] = fmaxf(fmaf(y3[e], aS[e], aB[e]), 0.f);
          }
          y0[e] = fmaxf(y0[e] + bw4[e], 0.f);
          y1[e] = fmaxf(y1[e] + bw4[e], 0.f);
          y2[e] = fmaxf(y2[e] + bw4[e], 0.f);
          y3[e] = fmaxf(y3[e] + bw4[e], 0.f);
        }
        __syncthreads();               // prev chunk's agg done
        f32x4* sy4 = (f32x4*)sSY;      // 16B/lane stride: conflict-free
        sy4[tid] = y0; sy4[tid + 256] = y1; sy4[tid + 512] = y2; sy4[tid + 768] = y3;
        {
          int lr = tid >> 4, c4 = (tid & 15) * 4;
          *(f32x4*)&sadj[lr * JC + c4] =
              *(const f32x4*)(adjb + (size_t)lr * NN + jc + c4);
        }
        if (jc + JC < NN) {            // pipeline: issue NEXT chunk now
          const f32x4* nb = xb4 + (jc + JC) * 16;
          cissue4(nb + tid, nb + tid + 256, nb + tid + 512, nb + tid + 768,
                  r0, r1, r2, r3);
        }
        __syncthreads();
        unsigned long long m0 = __ballot(sadj[(wv * 4 + 0) * JC + lane] != 0.f);
        unsigned long long m1 = __ballot(sadj[(wv * 4 + 1) * JC + lane] != 0.f);
        unsigned long long m2 = __ballot(sadj[(wv * 4 + 2) * JC + lane] != 0.f);
        unsigned long long m3 = __ballot(sadj[(wv * 4 + 3) * JC + lane] != 0.f);
        while (m0 | m1 | m2 | m3) {
          float v[8]; bool hb[8];
          unsigned long long mm[4] = {m0, m1, m2, m3};
#pragma unroll
          for (int k = 0; k < 4; ++k) {
            bool b0 = mm[k] != 0ull;
            int j0 = b0 ? __builtin_ctzll(mm[k]) : 0;
            mm[k] &= mm[k] - 1;
            bool b1 = mm[k] != 0ull;
            int j1 = b1 ? __builtin_ctzll(mm[k]) : 0;
            mm[k] &= mm[k] - 1;
            hb[2 * k] = b0; hb[2 * k + 1] = b1;
            v[2 * k] = sSY[j0 * DD + lane];
            v[2 * k + 1] = sSY[j1 * DD + lane];
          }
          m0 = mm[0]; m1 = mm[1]; m2 = mm[2]; m3 = mm[3];
          acc0 += (hb[0] ? v[0] : 0.f) + (hb[1] ? v[1] : 0.f);
          acc1 += (hb[2] ? v[2] : 0.f) + (hb[3] ? v[3] : 0.f);
          acc2 += (hb[4] ? v[4] : 0.f) + (hb[5] ? v[5] : 0.f);
          acc3 += (hb[6] ? v[6] : 0.f) + (hb[7] ? v[7] : 0.f);
        }
      }

      // h = (1+eps)*xv + agg   (xv from registers, not memory)
      sH[(wv * 4 + 0) * DD + lane] = acc0;
      sH[(wv * 4 + 1) * DD + lane] = acc1;
      sH[(wv * 4 + 2) * DD + lane] = acc2;
      sH[(wv * 4 + 3) * DD + lane] = acc3;
      __syncthreads();
      {
        f32x4 hv = *(f32x4*)&sH[row * DD + cb];
        f32x4 aS2 = {0,0,0,0}, aB2 = {0,0,0,0};
        if (l > 0) { aS2 = *(const f32x4*)&sSB[cb]; aB2 = *(const f32x4*)&sSB[64 + cb]; }
#pragma unroll
        for (int e = 0; e < 4; ++e) {
          float v = xown[e];
          if (l > 0) v = fmaxf(fmaf(v, aS2[e], aB2[e]), 0.f);
          hv[e] = fmaf(epv, v, hv[e]);
        }
        *(f32x4*)&sH[row * DD + cb] = hv;
      }
      __syncthreads();

      // MLP1: 16x128, thread = 2 rows x 4 cols
      {
        int rg = tid >> 5, c0 = (tid & 31) * 4;
        f32x4 bv = *(const f32x4*)&p.b1[l * D2 + c0];
        f32x4 o0 = bv, o1 = bv;
        for (int d = 0; d < DD; d += 4) {
          f32x4 s0 = *(const f32x4*)&sH[(rg * 2 + 0) * DD + d];
          f32x4 s1 = *(const f32x4*)&sH[(rg * 2 + 1) * DD + d];
          f32x4 w0 = *(const f32x4*)&sW[(d + 0) * D2 + c0];
          f32x4 w1 = *(const f32x4*)&sW[(d + 1) * D2 + c0];
          f32x4 w2 = *(const f32x4*)&sW[(d + 2) * D2 + c0];
          f32x4 w3 = *(const f32x4*)&sW[(d + 3) * D2 + c0];
          fma4(o0, s0[0], w0); fma4(o0, s0[1], w1); fma4(o0, s0[2], w2); fma4(o0, s0[3], w3);
          fma4(o1, s1[0], w0); fma4(o1, s1[1], w1); fma4(o1, s1[2], w2); fma4(o1, s1[3], w3);
        }
        *(f32x4*)&sH1[(rg * 2 + 0) * D2 + c0] = o0;
        *(f32x4*)&sH1[(rg * 2 + 1) * D2 + c0] = o1;
        *(f32x4*)&sSY[rg * D2 + c0] = o0 + o1;                  // psum [8][128]
        *(f32x4*)&sSY[1024 + rg * D2 + c0] = o0 * o0 + o1 * o1; // psq
      }
      __syncthreads();
      if (tid < D2) {
        float s = 0.f, q = 0.f;
#pragma unroll
        for (int g = 0; g < 8; ++g) { s += sSY[g * D2 + tid]; q += sSY[1024 + g * D2 + tid]; }
        float* a1 = accs + l * 384;
        atomicAdd(a1 + tid, s);
        atomicAdd(a1 + 128 + tid, q);
      }
    }
    bar_arrive(cnt);
    {  // stage W2(l) in the barrier gap
      const f32x4* w4 = (const f32x4*)(p.W2 + l * D2 * DD);
      f32x4* s4 = (f32x4*)sW;
#pragma unroll
      for (int i = 0; i < 8; ++i) s4[tid + i * 256] = w4[tid + i * 256];
    }
    bar_wait(cnt, tgt); tgt += 256;

    // ============ d: BN1+ReLU + MLP2 -> x (coherent) + xown, stats ============
    {
      if (tid < D2) {
        const float* a1 = accs + l * 384;
        float s = cload1(a1 + tid);
        float q = cload1(a1 + 128 + tid);
        float mean = s * (1.f / RTOT);
        float var = fmaf(-mean, mean, q * (1.f / RTOT));
        float sc = p.g1[l * D2 + tid] * rsqrtf(var + 1e-5f);
        sSB[tid] = sc;
        sSB[128 + tid] = fmaf(-mean, sc, p.be1[l * D2 + tid]);
      }
      __syncthreads();
#pragma unroll
      for (int ii = 0; ii < 2; ++ii) {     // BN+ReLU: sH1 -> sSY (stride 132)
        int i = tid + ii * 256;
        f32x4 v = ((const f32x4*)sH1)[i];
        int lr = i >> 5, c = (i & 31) * 4;
#pragma unroll
        for (int e = 0; e < 4; ++e)
          v[e] = fmaxf(fmaf(v[e], sSB[c + e], sSB[128 + c + e]), 0.f);
        *(f32x4*)&sSY[lr * 132 + c] = v;
      }
      __syncthreads();
      {
        f32x4 o = *(const f32x4*)&p.b2[l * DD + cb];
        for (int c = 0; c < D2; c += 4) {
          f32x4 s4 = *(const f32x4*)&sSY[row * 132 + c];
          f32x4 w0 = *(const f32x4*)&sW[(c + 0) * DD + cb];
          f32x4 w1 = *(const f32x4*)&sW[(c + 1) * DD + cb];
          f32x4 w2 = *(const f32x4*)&sW[(c + 2) * DD + cb];
          f32x4 w3 = *(const f32x4*)&sW[(c + 3) * DD + cb];
          fma4(o, s4[0], w0); fma4(o, s4[1], w1); fma4(o, s4[2], w2); fma4(o, s4[3], w3);
        }
        xown = o;
        cstore4(&p.x[(size_t)(gr0 + row) * DD + cb], o);
        *(f32x4*)&sSY[2176 + row * DD + cb] = o;
        *(f32x4*)&sSY[3200 + row * DD + cb] = o * o;
      }
      __syncthreads();
      if (tid < DD) {
        float s = 0.f, q = 0.f;
#pragma unroll
        for (int g = 0; g < 16; ++g) {
          s += sSY[2176 + g * DD + tid];
          q += sSY[3200 + g * DD + tid];
        }
        float* a2 = accs + l * 384;
        atomicAdd(a2 + 256 + tid, s);
        atomicAdd(a2 + 320 + tid, q);
      }
    }
    bar_arrive(cnt);
    if (l < 2) {  // stage W1(l+1) + bondW(l+1) in the barrier gap
      const f32x4* w4 = (const f32x4*)(p.W1 + (l + 1) * DD * D2);
      f32x4* s4 = (f32x4*)sW;
#pragma unroll
      for (int i = 0; i < 8; ++i) s4[tid + i * 256] = w4[tid + i * 256];
      if (tid < DD) sbw[tid] = p.bondW[(l + 1) * DD + tid];
    }
    bar_wait(cnt, tgt); tgt += 256;
  }

  // ================= final BN2 (no relu) from registers =================
  {
    if (tid < DD) {
      const float* a2 = accs + 2 * 384;
      float s = cload1(a2 + 256 + tid);
      float q = cload1(a2 + 320 + tid);
      float mean = s * (1.f / RTOT);
      float var = fmaf(-mean, mean, q * (1.f / RTOT));
      float sc = p.gbn[2 * DD + tid] * rsqrtf(var + 1e-5f);
      sSB[tid] = sc;
      sSB[64 + tid] = fmaf(-mean, sc, p.bbn[2 * DD + tid]);
    }
    __syncthreads();
    f32x4 v = xown;
#pragma unroll
    for (int e = 0; e < 4; ++e) v[e] = fmaf(v[e], sSB[cb + e], sSB[64 + cb + e]);
    *(f32x4*)&p.out[(size_t)(gr0 + row) * DD + cb] = v;
  }
}

extern "C" void kernel_launch(void* const* d_in, const int* in_sizes, int n_in,
                              void* d_out, int out_size, void* d_ws, size_t ws_size,
                              hipStream_t stream) {
  Params prm;
  prm.fea  = (const float*)d_in[0];
  prm.adj  = (const float*)d_in[1];
  prm.encW = (const float*)d_in[2];
  prm.encb = (const float*)d_in[3];
  prm.bondW= (const float*)d_in[4];
  prm.eps  = (const float*)d_in[5];
  prm.W1   = (const float*)d_in[6];
  prm.b1   = (const float*)d_in[7];
  prm.g1   = (const float*)d_in[8];
  prm.be1  = (const float*)d_in[9];
  prm.W2   = (const float*)d_in[10];
  prm.b2   = (const float*)d_in[11];
  prm.gbn  = (const float*)d_in[12];
  prm.bbn  = (const float*)d_in[13];
  prm.out  = (float*)d_out;
  float* ws = (float*)d_ws;
  prm.x    = ws;                 // 262144 floats
  prm.ctrl = ws + 262144;        // counter + 3*384 stat accumulators

  hipMemsetAsync(prm.ctrl, 0, 8192, stream);
  fused<<<GB, 256, 0, stream>>>(prm);
}